// Round 19
// baseline (250.744 us; speedup 1.0000x reference)
//
#include <hip/hip_runtime.h>
#include <hip/hip_bf16.h>
#include <math.h>

#define DIM 128
#define QB 128
#define MB 64
#define NSPLIT 32
#define KSEL 16
#define KOWN 4
#define RESCORE 32
#define IDXMASK 0x1FFFu
#define KEYMASK 0xFFFFE000u
#define M2MAX 3200

using bf16x8 = __attribute__((ext_vector_type(8))) short;
using f32x4  = __attribute__((ext_vector_type(4))) float;

__device__ inline unsigned short f2bf(float f) {
  __hip_bfloat16 h = __float2bfloat16(f);   // RNE
  return __builtin_bit_cast(unsigned short, h);
}
__device__ inline unsigned uminu(unsigned a, unsigned b) {
  return __builtin_elementwise_min(a, b);   // v_min_u32
}
__device__ inline unsigned umaxu(unsigned a, unsigned b) {
  return __builtin_elementwise_max(a, b);   // v_max_u32
}
__device__ inline unsigned long long umin64(unsigned long long a,
                                            unsigned long long b) {
  return __builtin_elementwise_min(a, b);
}

__device__ inline f32x4 mfma16(bf16x8 a, bf16x8 b, f32x4 c) {
  return __builtin_amdgcn_mfma_f32_16x16x32_bf16(a, b, c, 0, 0, 0);
}

__device__ inline void gload_lds16(const void* g, void* l) {
  __builtin_amdgcn_global_load_lds(
      (const __attribute__((address_space(1))) void*)g,
      (__attribute__((address_space(3))) void*)l, 16, 0, 0);
}

__device__ inline void ins4(unsigned (&ks)[KOWN], unsigned c) {
  #pragma unroll
  for (int i = 0; i < KOWN; ++i) {
    const unsigned lo = uminu(c, ks[i]);
    c = umaxu(c, ks[i]);
    ks[i] = lo;
  }
}

// ---------------------------------------------------------------------------
// Kernel 1 (fused): Poincare transform. NO main-loop LDS:
//   wave owns 16 output cols (W via wave-uniform scalar loads); lane owns
//   rows {2l, 2l+1} read DIRECTLY from global (L1/L2-served). h stays in
//   registers through tanh/scale/store. LDS = 4.6 KB -> 4 blocks/CU
//   (32 waves/CU; R18's 68.6 KB X-tile capped it at 16 waves/CU).
//   FMA/tanh order identical to R18 -> P bit-identical.
//   Pmbf store pre-swizzled: granule g at position g ^ (row & 15).
// ---------------------------------------------------------------------------
__global__ __launch_bounds__(512) void poincare2_k(
    const float* __restrict__ Xm, int Rm,
    const float* __restrict__ Xq, int Rq,
    const float* __restrict__ W, const float* __restrict__ bias,
    float* __restrict__ Pm, float* __restrict__ Pm2,
    float* __restrict__ Pm2s, int npadm,
    unsigned short* __restrict__ Pmbf,
    float* __restrict__ Pq, float* __restrict__ Pq2, int nbm)
{
  __shared__ float nrm[128 * 8];         // 4 KB partials [row][wave]
  __shared__ float norm2l[128];

  const int t  = threadIdx.x;
  const int l  = t & 63;
  const int wv_ = t >> 6;
  const int jw = __builtin_amdgcn_readfirstlane(wv_ * 16);

  const bool ismem = (int)blockIdx.x < nbm;
  const float* X = ismem ? Xm : Xq;
  const int    R = ismem ? Rm : Rq;
  float*       P  = ismem ? Pm  : Pq;
  float*       P2 = ismem ? Pm2 : Pq2;
  unsigned short* Pbf = ismem ? Pmbf : nullptr;
  const int rbase = (ismem ? blockIdx.x : (blockIdx.x - nbm)) * 128;

  const int row0 = rbase + 2 * l;
  const int row1 = row0 + 1;
  const float* x0p = X + (size_t)min(row0, R - 1) * DIM;   // clamp tails
  const float* x1p = X + (size_t)min(row1, R - 1) * DIM;

  float acc0[16], acc1[16];
  #pragma unroll
  for (int u = 0; u < 16; ++u) {
    const float b = bias[jw + u];
    acc0[u] = b; acc1[u] = b;
  }

  const float* Wb = W + jw * DIM;        // wave-uniform base -> scalar loads
  #pragma unroll 4
  for (int k4 = 0; k4 < 32; ++k4) {
    const float4 xv0 = *(const float4*)(x0p + k4 * 4);
    const float4 xv1 = *(const float4*)(x1p + k4 * 4);
    #pragma unroll
    for (int u = 0; u < 16; ++u) {
      const float4 wvv = *(const float4*)(Wb + u * DIM + k4 * 4);
      acc0[u] = fmaf(xv0.x, wvv.x, acc0[u]);
      acc0[u] = fmaf(xv0.y, wvv.y, acc0[u]);
      acc0[u] = fmaf(xv0.z, wvv.z, acc0[u]);
      acc0[u] = fmaf(xv0.w, wvv.w, acc0[u]);
      acc1[u] = fmaf(xv1.x, wvv.x, acc1[u]);
      acc1[u] = fmaf(xv1.y, wvv.y, acc1[u]);
      acc1[u] = fmaf(xv1.z, wvv.z, acc1[u]);
      acc1[u] = fmaf(xv1.w, wvv.w, acc1[u]);
    }
  }

  // tanh (EXACT) + per-(row, wave) partial norms
  float pn0 = 0.f, pn1 = 0.f;
  #pragma unroll
  for (int u = 0; u < 16; ++u) {
    acc0[u] = tanhf(acc0[u]); pn0 = fmaf(acc0[u], acc0[u], pn0);
    acc1[u] = tanhf(acc1[u]); pn1 = fmaf(acc1[u], acc1[u], pn1);
  }
  nrm[(2 * l) * 8 + wv_]     = pn0;
  nrm[(2 * l + 1) * 8 + wv_] = pn1;
  __syncthreads();
  if (t < 128) {
    float s = 0.f;
    #pragma unroll
    for (int j = 0; j < 8; ++j) s += nrm[t * 8 + j];
    norm2l[t] = s;
    const int row = rbase + t;
    if (row < R) {
      const float nm = sqrtf(s);
      const float sc = (nm > 0.9f) ? (0.9f / nm) : 1.0f;
      const float p2v = s * sc * sc;
      P2[row] = p2v;
      if (ismem) Pm2s[row] = fmaf(0.5f, p2v, 1.0f);
    } else if (ismem && row < npadm) {
      Pm2s[row] = __int_as_float(0x7f800000);   // +inf: exclude padded rows
    }
  }
  __syncthreads();

  // scale + store straight from registers
  const int g0 = jw >> 3;                // first 16B granule of this col block
  {
    if (row0 < R) {
      const float n2 = norm2l[2 * l];
      const float nm = sqrtf(n2);
      const float sc = (nm > 0.9f) ? (0.9f / nm) : 1.0f;
      float o[16];
      #pragma unroll
      for (int u = 0; u < 16; ++u) o[u] = acc0[u] * sc;
      #pragma unroll
      for (int u4 = 0; u4 < 4; ++u4)
        *(float4*)&P[(size_t)row0 * DIM + jw + u4 * 4] =
            make_float4(o[u4*4], o[u4*4+1], o[u4*4+2], o[u4*4+3]);
      if (Pbf) {
        uint4 pa, pb;
        pa.x = (unsigned)f2bf(o[0])  | ((unsigned)f2bf(o[1])  << 16);
        pa.y = (unsigned)f2bf(o[2])  | ((unsigned)f2bf(o[3])  << 16);
        pa.z = (unsigned)f2bf(o[4])  | ((unsigned)f2bf(o[5])  << 16);
        pa.w = (unsigned)f2bf(o[6])  | ((unsigned)f2bf(o[7])  << 16);
        pb.x = (unsigned)f2bf(o[8])  | ((unsigned)f2bf(o[9])  << 16);
        pb.y = (unsigned)f2bf(o[10]) | ((unsigned)f2bf(o[11]) << 16);
        pb.z = (unsigned)f2bf(o[12]) | ((unsigned)f2bf(o[13]) << 16);
        pb.w = (unsigned)f2bf(o[14]) | ((unsigned)f2bf(o[15]) << 16);
        *(uint4*)&Pmbf[(size_t)row0 * DIM + ((g0       ^ (row0 & 15)) << 3)] = pa;
        *(uint4*)&Pmbf[(size_t)row0 * DIM + (((g0 + 1) ^ (row0 & 15)) << 3)] = pb;
      }
    }
    if (row1 < R) {
      const float n2 = norm2l[2 * l + 1];
      const float nm = sqrtf(n2);
      const float sc = (nm > 0.9f) ? (0.9f / nm) : 1.0f;
      float o[16];
      #pragma unroll
      for (int u = 0; u < 16; ++u) o[u] = acc1[u] * sc;
      #pragma unroll
      for (int u4 = 0; u4 < 4; ++u4)
        *(float4*)&P[(size_t)row1 * DIM + jw + u4 * 4] =
            make_float4(o[u4*4], o[u4*4+1], o[u4*4+2], o[u4*4+3]);
      if (Pbf) {
        uint4 pa, pb;
        pa.x = (unsigned)f2bf(o[0])  | ((unsigned)f2bf(o[1])  << 16);
        pa.y = (unsigned)f2bf(o[2])  | ((unsigned)f2bf(o[3])  << 16);
        pa.z = (unsigned)f2bf(o[4])  | ((unsigned)f2bf(o[5])  << 16);
        pa.w = (unsigned)f2bf(o[6])  | ((unsigned)f2bf(o[7])  << 16);
        pb.x = (unsigned)f2bf(o[8])  | ((unsigned)f2bf(o[9])  << 16);
        pb.y = (unsigned)f2bf(o[10]) | ((unsigned)f2bf(o[11]) << 16);
        pb.z = (unsigned)f2bf(o[12]) | ((unsigned)f2bf(o[13]) << 16);
        pb.w = (unsigned)f2bf(o[14]) | ((unsigned)f2bf(o[15]) << 16);
        *(uint4*)&Pmbf[(size_t)row1 * DIM + ((g0       ^ (row1 & 15)) << 3)] = pa;
        *(uint4*)&Pmbf[(size_t)row1 * DIM + (((g0 + 1) ^ (row1 & 15)) << 3)] = pb;
      }
    }
  }
}

// ---------------------------------------------------------------------------
// Kernel 2: bf16-MFMA approx scoring, QB=128, 3-buffer counted-vmcnt pipeline
//   (unchanged from the passing R17/R18 version; ~110 µs).
// ---------------------------------------------------------------------------
template<bool USEBF>
__global__ __launch_bounds__(512, 2) void score_topk_k(
    const float* __restrict__ Pq,
    const float* __restrict__ Pm, const float* __restrict__ Pm2s,
    const unsigned short* __restrict__ Pmbf,
    int N, int splitlen, unsigned* __restrict__ splitTop)
{
  __shared__ __align__(16) unsigned short Ml[3][MB * DIM];  // 3 x 16 KB
  __shared__ float m2all[M2MAX];                            // 12.8 KB

  const int t = threadIdx.x;
  const int lane = t & 63;
  const int w = t >> 6, wr = w >> 1, wc = w & 1;   // 4 q-groups x 2 m-halves
  const int split = blockIdx.x;
  const int qbase = blockIdx.y * QB;
  const int mlo = split * splitlen;                // multiple of MB
  const int mhi = min(mlo + splitlen, N);
  const int ntiles = (mhi - mlo + MB - 1) / MB;

  // TWO persistent NEGATED Q fragments per wave: rows wr*32+s*16+..
  bf16x8 qf[2][4];
  #pragma unroll
  for (int s = 0; s < 2; ++s) {
    const int qrow = qbase + wr * 32 + s * 16 + (lane & 15);
    #pragma unroll
    for (int ks = 0; ks < 4; ++ks) {
      const float* src = &Pq[(size_t)qrow * DIM + ks * 32 + (lane >> 4) * 8];
      float4 lo = *(const float4*)src;
      float4 hi = *(const float4*)(src + 4);
      bf16x8 v;
      v[0] = (short)f2bf(-lo.x); v[1] = (short)f2bf(-lo.y);
      v[2] = (short)f2bf(-lo.z); v[3] = (short)f2bf(-lo.w);
      v[4] = (short)f2bf(-hi.x); v[5] = (short)f2bf(-hi.y);
      v[6] = (short)f2bf(-hi.z); v[7] = (short)f2bf(-hi.w);
      qf[s][ks] = v;
    }
  }

  // whole-split C-init values into LDS (once, before the pipeline starts)
  for (int i = t; i < splitlen; i += 512) m2all[i] = Pm2s[mlo + i];

  // staging: wave stages rows w*8 .. w*8+7 (2 x gload_lds16 of 4 rows each)
  const size_t soff0 = (size_t)(w * 8 + (lane >> 4)) * DIM + ((lane & 15) << 3);
  const size_t soff1 = soff0 + 4 * DIM;

  auto stageU = [&](int tilei, int buf) {
    const unsigned short* b = Pmbf + (size_t)(mlo + tilei * MB) * DIM;
    gload_lds16(b + soff0, &Ml[buf][(w * 8) * DIM]);
    gload_lds16(b + soff1, &Ml[buf][(w * 8 + 4) * DIM]);
  };
  // !USEBF fallback staging (fp32 -> bf16 through regs)
  uint4 sv0, sv1;
  auto stageF_load = [&](int tilei) {
    const int fr = t >> 3, fe = t & 7;
    const float* src = Pm + (size_t)(mlo + tilei * MB + fr) * DIM + fe * 16;
    float4 a0 = *(const float4*)(src + 0);
    float4 a1 = *(const float4*)(src + 4);
    float4 a2 = *(const float4*)(src + 8);
    float4 a3 = *(const float4*)(src + 12);
    sv0.x = (unsigned)f2bf(a0.x) | ((unsigned)f2bf(a0.y) << 16);
    sv0.y = (unsigned)f2bf(a0.z) | ((unsigned)f2bf(a0.w) << 16);
    sv0.z = (unsigned)f2bf(a1.x) | ((unsigned)f2bf(a1.y) << 16);
    sv0.w = (unsigned)f2bf(a1.z) | ((unsigned)f2bf(a1.w) << 16);
    sv1.x = (unsigned)f2bf(a2.x) | ((unsigned)f2bf(a2.y) << 16);
    sv1.y = (unsigned)f2bf(a2.z) | ((unsigned)f2bf(a2.w) << 16);
    sv1.z = (unsigned)f2bf(a3.x) | ((unsigned)f2bf(a3.y) << 16);
    sv1.w = (unsigned)f2bf(a3.z) | ((unsigned)f2bf(a3.w) << 16);
  };
  auto stageF_write = [&](int buf) {
    const int fr = t >> 3, fe = t & 7;
    char* base = (char*)&Ml[buf][0] + fr * 256;
    *(uint4*)(base + (((2 * fe)     ^ (fr & 15)) << 4)) = sv0;
    *(uint4*)(base + (((2 * fe + 1) ^ (fr & 15)) << 4)) = sv1;
  };

  unsigned keys[2][4][KOWN];
  #pragma unroll
  for (int s = 0; s < 2; ++s)
    #pragma unroll
    for (int r = 0; r < 4; ++r)
      #pragma unroll
      for (int i = 0; i < KOWN; ++i) keys[s][r][i] = 0xFFFFFFFFu;

  const int mcol = wc * 32 + (lane & 15);
  const int rowA = mcol, rowB = mcol + 16;

  auto compute = [&](int tile, const unsigned short* cur) {
    const float ca = m2all[tile * MB + mcol];
    const float cb = m2all[tile * MB + mcol + 16];
    // C-init: acc = 0.5*m2+1; with A = -q, result = (m2+2)/2 - dot = d2/2
    f32x4 a00 = (f32x4){ca, ca, ca, ca};
    f32x4 a01 = (f32x4){cb, cb, cb, cb};
    f32x4 a10 = (f32x4){ca, ca, ca, ca};
    f32x4 a11 = (f32x4){cb, cb, cb, cb};
    __builtin_amdgcn_s_setprio(1);
    #pragma unroll
    for (int ks = 0; ks < 4; ++ks) {
      const int kb = ks * 64 + (lane >> 4) * 16;
      bf16x8 bfrA = *(const bf16x8*)((const char*)cur + rowA * 256 +
                                     (kb ^ ((rowA & 15) << 4)));
      bf16x8 bfrB = *(const bf16x8*)((const char*)cur + rowB * 256 +
                                     (kb ^ ((rowB & 15) << 4)));
      a00 = mfma16(qf[0][ks], bfrA, a00);
      a01 = mfma16(qf[0][ks], bfrB, a01);
      a10 = mfma16(qf[1][ks], bfrA, a10);
      a11 = mfma16(qf[1][ks], bfrB, a11);
    }
    __builtin_amdgcn_s_setprio(0);
    const unsigned idx0 = (unsigned)(tile * MB + mcol);
    #pragma unroll
    for (int r = 0; r < 4; ++r) {
      ins4(keys[0][r], (__float_as_uint(a00[r]) & KEYMASK) | idx0);
      ins4(keys[0][r], (__float_as_uint(a01[r]) & KEYMASK) | (idx0 + 16));
      ins4(keys[1][r], (__float_as_uint(a10[r]) & KEYMASK) | idx0);
      ins4(keys[1][r], (__float_as_uint(a11[r]) & KEYMASK) | (idx0 + 16));
    }
  };

  if constexpr (USEBF) {
    __syncthreads();                 // m2all visible; VMEM fully drained
    stageU(0, 0);
    if (ntiles > 1) stageU(1, 1);
    int cur = 0;
    for (int i = 0; i < ntiles; ++i) {
      // my stage(i) done (stage(i+1)'s 2 ops may remain in flight)
      if (i < ntiles - 1) asm volatile("s_waitcnt vmcnt(2)" ::: "memory");
      else                asm volatile("s_waitcnt vmcnt(0)" ::: "memory");
      __builtin_amdgcn_s_barrier();  // ALL waves' stage(i) done; all
                                     // compute(i-1) reads finished
      __builtin_amdgcn_sched_barrier(0);
      int nb = cur + 2; if (nb >= 3) nb -= 3;      // buffer of tile i-1, free
      if (i + 2 < ntiles) stageU(i + 2, nb);
      compute(i, &Ml[cur][0]);
      cur = (cur + 1 == 3) ? 0 : cur + 1;
    }
  } else {
    stageF_load(0);
    stageF_write(0);
    __syncthreads();
    for (int i = 0; i < ntiles; ++i) {
      const int cur = i & 1;
      const bool more = (i + 1 < ntiles);
      if (more) stageF_load(i + 1);
      compute(i, &Ml[cur][0]);
      __syncthreads();
      if (more) stageF_write(cur ^ 1);
      __syncthreads();
    }
  }

  // ---- emission: per (s,r) q-slot 16-lane tournament -> sorted-8; the two
  // wc-groups of each q meet in LDS; wc=0 waves produce top-8 of the 16.
  unsigned* mb = (unsigned*)&Ml[0][0];            // 128 q x 16 u32 = 8 KB
  __syncthreads();                                // all tile reads done
  #pragma unroll
  for (int s = 0; s < 2; ++s)
    #pragma unroll
    for (int r = 0; r < 4; ++r) {
      unsigned k0 = keys[s][r][0], k1 = keys[s][r][1];
      unsigned k2 = keys[s][r][2], k3 = keys[s][r][3];
      unsigned out = 0xFFFFFFFFu;
      for (int round = 0; round < 8; ++round) {
        unsigned g = k0;
        g = uminu(g, __shfl_xor(g, 1, 16));
        g = uminu(g, __shfl_xor(g, 2, 16));
        g = uminu(g, __shfl_xor(g, 4, 16));
        g = uminu(g, __shfl_xor(g, 8, 16));
        const bool mine = (k0 == g);
        k0 = mine ? k1 : k0;
        k1 = mine ? k2 : k1;
        k2 = mine ? k3 : k2;
        k3 = mine ? 0xFFFFFFFFu : k3;
        if ((lane & 15) == round) out = g;
      }
      const int lq = wr * 32 + s * 16 + (lane >> 4) * 4 + r;
      if ((lane & 15) < 8) mb[lq * 16 + wc * 8 + (lane & 15)] = out;
    }
  __syncthreads();
  if (wc == 0 && lane < 32) {
    const int lq = wr * 32 + lane;
    unsigned s8[8];
    #pragma unroll
    for (int i = 0; i < 8; ++i) s8[i] = 0xFFFFFFFFu;
    const unsigned* src = mb + lq * 16;
    #pragma unroll
    for (int i = 0; i < 16; ++i) {
      unsigned c = src[i];
      #pragma unroll
      for (int j = 0; j < 8; ++j) {
        const unsigned lo = uminu(c, s8[j]);
        c = umaxu(c, s8[j]);
        s8[j] = lo;
      }
    }
    unsigned* dst = &splitTop[((size_t)(qbase + lq) * NSPLIT + split) * 8];
    *(uint4*)dst       = make_uint4(s8[0], s8[1], s8[2], s8[3]);
    *((uint4*)dst + 1) = make_uint4(s8[4], s8[5], s8[6], s8[7]);
  }
}

// ---------------------------------------------------------------------------
// Kernel 3: 4 queries per block, one wave per query.
//   merge 256 candidates (32 sorted-8 streams) -> approx top-32 ->
//   EXACT fp32 rescore -> top-16, softmax, gather.
// ---------------------------------------------------------------------------
__global__ __launch_bounds__(256) void finalize_k(
    const unsigned* __restrict__ splitTop,
    const float* __restrict__ Pq, const float* __restrict__ Pq2,
    const float* __restrict__ Pm, const float* __restrict__ Pm2,
    const float* __restrict__ memOut, int N, int splitlen,
    float* __restrict__ outW, float* __restrict__ outO)
{
  const int wv   = threadIdx.x >> 6;     // wave 0..3 -> query
  const int lane = threadIdx.x & 63;
  const int q = blockIdx.x * 4 + wv;

  __shared__ unsigned      sKey[4][RESCORE];
  __shared__ unsigned char sSrc[4][RESCORE];
  __shared__ unsigned long long sKeyx[4][RESCORE];
  __shared__ unsigned long long sSel[4][KSEL];
  __shared__ float sEl[4][KSEL];

  // phase A: lane < 32 owns split stream `lane` (8 keys, sorted ascending)
  {
    unsigned a[8];
    if (lane < NSPLIT) {
      const unsigned* gp = splitTop + (size_t)q * (NSPLIT * 8) + lane * 8;
      uint4 lo = *(const uint4*)gp;
      uint4 hi = *(const uint4*)(gp + 4);
      a[0] = lo.x; a[1] = lo.y; a[2] = lo.z; a[3] = lo.w;
      a[4] = hi.x; a[5] = hi.y; a[6] = hi.z; a[7] = hi.w;
    } else {
      #pragma unroll
      for (int i = 0; i < 8; ++i) a[i] = 0xFFFFFFFFu;
    }
    for (int r = 0; r < RESCORE; ++r) {
      unsigned g = a[0];
      g = uminu(g, __shfl_xor(g, 1));
      g = uminu(g, __shfl_xor(g, 2));
      g = uminu(g, __shfl_xor(g, 4));
      g = uminu(g, __shfl_xor(g, 8));
      g = uminu(g, __shfl_xor(g, 16));
      g = uminu(g, __shfl_xor(g, 32));
      unsigned long long mask = __ballot(a[0] == g);
      const int fl = __ffsll((unsigned long long)mask) - 1;
      if (lane == fl) {
        #pragma unroll
        for (int i = 0; i < 7; ++i) a[i] = a[i + 1];
        a[7] = 0xFFFFFFFFu;
      }
      if (lane == 0) { sKey[wv][r] = g; sSrc[wv][r] = (unsigned char)fl; }
    }
  }

  // phase B: exact fp32 rescore; 4 passes x 8 cands x 8 lanes each
  #pragma unroll
  for (int p = 0; p < 4; ++p) {
    const int g8 = p * 8 + (lane >> 3), e = lane & 7;
    const int gidx = (int)sSrc[wv][g8] * splitlen + (int)(sKey[wv][g8] & IDXMASK);
    const float4* qr = (const float4*)&Pq[(size_t)q * DIM];
    const float4* mr = (const float4*)&Pm[(size_t)gidx * DIM];
    float s = 0.f;
    #pragma unroll
    for (int u = 0; u < 4; ++u) {
      float4 a = qr[e * 4 + u], b = mr[e * 4 + u];
      s = fmaf(a.x, b.x, s); s = fmaf(a.y, b.y, s);
      s = fmaf(a.z, b.z, s); s = fmaf(a.w, b.w, s);
    }
    s += __shfl_xor(s, 1, 8);
    s += __shfl_xor(s, 2, 8);
    s += __shfl_xor(s, 4, 8);
    if (e == 0) {
      float d2 = (Pq2[q] + Pm2[gidx]) - 2.0f * s;
      float dist = sqrtf(fmaxf(d2, 1e-12f));
      sKeyx[wv][g8] =
          (((unsigned long long)__float_as_uint(dist)) << 32) | (unsigned)gidx;
    }
  }

  // phase C: exact top-16 of the 32 (keys unique: low bits = gidx)
  {
    unsigned long long kk = (lane < RESCORE) ? sKeyx[wv][lane] : ~0ull;
    for (int r = 0; r < KSEL; ++r) {
      unsigned long long g = kk;
      g = umin64(g, __shfl_xor(g, 1));
      g = umin64(g, __shfl_xor(g, 2));
      g = umin64(g, __shfl_xor(g, 4));
      g = umin64(g, __shfl_xor(g, 8));
      g = umin64(g, __shfl_xor(g, 16));
      g = umin64(g, __shfl_xor(g, 32));
      if (kk == g) kk = ~0ull;
      if (lane == 0) sSel[wv][r] = g;
    }
  }

  if (lane < KSEL) {
    const float d  = __uint_as_float((unsigned)(sSel[wv][lane] >> 32));
    const float d0 = __uint_as_float((unsigned)(sSel[wv][0] >> 32));
    sEl[wv][lane] = expf((d0 - d) * 10.0f);      // -(d/0.1) + d0/0.1
  }
  if (lane < KSEL) {
    float sum = 0.f;
    #pragma unroll
    for (int i = 0; i < KSEL; ++i) sum += sEl[wv][i];
    outW[(size_t)q * KSEL + lane] = sEl[wv][lane] / sum;
  }

  #pragma unroll
  for (int i = 0; i < 8; ++i) {
    const int f4 = lane + i * 64;
    const int r = f4 >> 5, c4 = f4 & 31;
    const int idx = (int)(sSel[wv][r] & 0xffffffffu);
    *(float4*)&outO[((size_t)q * KSEL + r) * DIM + c4 * 4] =
        *(const float4*)&memOut[(size_t)idx * DIM + c4 * 4];
  }
}

// ---------------------------------------------------------------------------
extern "C" void kernel_launch(void* const* d_in, const int* in_sizes, int n_in,
                              void* d_out, int out_size, void* d_ws, size_t ws_size,
                              hipStream_t stream)
{
  const float* query   = (const float*)d_in[0];
  const float* W       = (const float*)d_in[1];
  const float* bias    = (const float*)d_in[2];
  const float* mem_emb = (const float*)d_in[3];
  const float* mem_out = (const float*)d_in[4];
  const int B = in_sizes[0] / DIM;   // 2048
  const int N = in_sizes[3] / DIM;   // 100000

  // tile-aligned split length: mlo = split*splitlen is a multiple of MB
  const int splitlen = ((N + NSPLIT * MB - 1) / (NSPLIT * MB)) * MB;   // 3136
  const int N_pad2 = NSPLIT * splitlen;                                // 100352

  // ws (80.9 MB): Pm[N] | Pm2[N] | Pm2s[N_pad2] | Pq | Pq2 |
  //               splitTop[B*NSPLIT*8] | Pmbf[N_pad2*128]
  float* ws  = (float*)d_ws;
  float* Pm  = ws;
  float* Pm2 = Pm + (size_t)N * DIM;
  float* Pm2s = Pm2 + N;
  float* Pq  = Pm2s + N_pad2;
  float* Pq2 = Pq + (size_t)B * DIM;
  unsigned* splitTop = (unsigned*)(Pq2 + B);
  unsigned short* Pmbf = (unsigned short*)(splitTop + (size_t)B * NSPLIT * 8);
  const size_t need_bf = (size_t)((char*)(Pmbf + (size_t)N_pad2 * DIM) - (char*)d_ws);
  const bool usebf = ws_size >= need_bf;

  float* outW = (float*)d_out;
  float* outO = outW + (size_t)B * KSEL;

  // 1) fused Poincare transforms; grid covers padded mem rows for Pm2s +inf
  const int nbm = (N_pad2 + 127) / 128;
  const int nbq = (B + 127) / 128;
  poincare2_k<<<dim3(nbm + nbq), dim3(512), 0, stream>>>(
      mem_emb, N, query, B, W, bias, Pm, Pm2, Pm2s, N_pad2,
      usebf ? Pmbf : nullptr, Pq, Pq2, nbm);

  // 2) bf16-MFMA approx scoring + per-(q,split) top-8
  //    x = split (fast): 32%8==0 -> 4 fixed splits per XCD (3.2MB < L2)
  dim3 grid2(NSPLIT, B / QB);
  if (usebf)
    score_topk_k<true><<<grid2, dim3(512), 0, stream>>>(Pq, Pm, Pm2s, Pmbf, N,
                                                        splitlen, splitTop);
  else
    score_topk_k<false><<<grid2, dim3(512), 0, stream>>>(Pq, Pm, Pm2s, nullptr, N,
                                                         splitlen, splitTop);

  // 3) merge + exact rescore + softmax + gather (wave per query)
  finalize_k<<<dim3(B / 4), dim3(256), 0, stream>>>(splitTop, Pq, Pq2, Pm, Pm2,
                                                    mem_out, N, splitlen,
                                                    outW, outO);
}

// Round 20
// 191.263 us; speedup vs baseline: 1.3110x; 1.3110x over previous
//
#include <hip/hip_runtime.h>
#include <hip/hip_bf16.h>
#include <math.h>

#define DIM 128
#define QB 128
#define MB 64
#define NSPLIT 32
#define KSEL 16
#define KOWN 4
#define RESCORE 32
#define IDXMASK 0x1FFFu
#define KEYMASK 0xFFFFE000u
#define M2MAX 3200

using bf16x8 = __attribute__((ext_vector_type(8))) short;
using f32x4  = __attribute__((ext_vector_type(4))) float;

__device__ inline unsigned short f2bf(float f) {
  __hip_bfloat16 h = __float2bfloat16(f);   // RNE
  return __builtin_bit_cast(unsigned short, h);
}
__device__ inline unsigned uminu(unsigned a, unsigned b) {
  return __builtin_elementwise_min(a, b);   // v_min_u32
}
__device__ inline unsigned umaxu(unsigned a, unsigned b) {
  return __builtin_elementwise_max(a, b);   // v_max_u32
}
__device__ inline unsigned umed3(unsigned a, unsigned b, unsigned c) {
  unsigned r;
  asm("v_med3_u32 %0, %1, %2, %3" : "=v"(r) : "v"(a), "v"(b), "v"(c));
  return r;
}
__device__ inline unsigned long long umin64(unsigned long long a,
                                            unsigned long long b) {
  return __builtin_elementwise_min(a, b);
}

__device__ inline f32x4 mfma16(bf16x8 a, bf16x8 b, f32x4 c) {
  return __builtin_amdgcn_mfma_f32_16x16x32_bf16(a, b, c, 0, 0, 0);
}

__device__ inline void gload_lds16(const void* g, void* l) {
  __builtin_amdgcn_global_load_lds(
      (const __attribute__((address_space(1))) void*)g,
      (__attribute__((address_space(3))) void*)l, 16, 0, 0);
}

// sorted-4 insert via med3: ks ascending; n0=min, n_i=med3(c,k_{i-1},k_i).
// 4 VALU (3 independent med3) vs 8-deep min/max chain.
__device__ inline void ins4(unsigned (&ks)[KOWN], unsigned c) {
  const unsigned n0 = uminu(c, ks[0]);
  const unsigned n1 = umed3(c, ks[0], ks[1]);
  const unsigned n2 = umed3(c, ks[1], ks[2]);
  const unsigned n3 = umed3(c, ks[2], ks[3]);
  ks[0] = n0; ks[1] = n1; ks[2] = n2; ks[3] = n3;
}

// ---------------------------------------------------------------------------
// Kernel 1 (fused): Poincare transform for mem rows AND query rows in one grid
//   (R16/R17 version — proven best). P = clip_ball(tanh(X @ W^T + b)),
//   P2 = ||P||^2 (EXACT tanhf). bf16 copy PRE-SWIZZLED (chunk = cg^(row&15)).
//   Pm2s = 0.5*m2+1; +inf for padded rows [N, npadm).
// ---------------------------------------------------------------------------
__global__ __launch_bounds__(512) void poincare2_k(
    const float* __restrict__ Xm, int Rm,
    const float* __restrict__ Xq, int Rq,
    const float* __restrict__ W, const float* __restrict__ bias,
    float* __restrict__ Pm, float* __restrict__ Pm2,
    float* __restrict__ Pm2s, int npadm,
    unsigned short* __restrict__ Pmbf,
    float* __restrict__ Pq, float* __restrict__ Pq2, int nbm)
{
  __shared__ float Wl[DIM * DIM];        // 64 KB, swizzled
  __shared__ float nrm[128 * 17];        // partials [row][cg]
  __shared__ float norm2l[128];

  const int t  = threadIdx.x;
  const int cg = t & 15;                 // 0..15 (8 cols each)
  const int rg = t >> 4;                 // 0..31 (rows rg + 32v)

  const bool ismem = (int)blockIdx.x < nbm;
  const float* X = ismem ? Xm : Xq;
  const int    R = ismem ? Rm : Rq;
  float*       P  = ismem ? Pm  : Pq;
  float*       P2 = ismem ? Pm2 : Pq2;
  unsigned short* Pbf = ismem ? Pmbf : nullptr;
  const int rbase = (ismem ? blockIdx.x : (blockIdx.x - nbm)) * 128;

  for (int i = t; i < DIM * 32; i += 512) {
    const int j = i >> 5, c = i & 31;
    const float4 v = *(const float4*)&W[j * DIM + c * 4];
    *(float4*)&Wl[j * DIM + ((c ^ ((j >> 3) & 7)) << 2)] = v;
  }
  float bj[8];
  #pragma unroll
  for (int u = 0; u < 8; ++u) bj[u] = bias[cg * 8 + u];

  const float* xr[4];
  #pragma unroll
  for (int v = 0; v < 4; ++v) {
    int row = rbase + rg + 32 * v;
    if (row > R - 1) row = R - 1;        // clamp; invalid rows never stored
    xr[v] = X + (size_t)row * DIM;
  }
  __syncthreads();

  float acc[4][8];
  #pragma unroll
  for (int v = 0; v < 4; ++v)
    #pragma unroll
    for (int u = 0; u < 8; ++u) acc[v][u] = bj[u];

  #pragma unroll 2
  for (int k4 = 0; k4 < 32; ++k4) {
    float4 xv[4], wv[8];
    #pragma unroll
    for (int v = 0; v < 4; ++v) xv[v] = *(const float4*)&xr[v][k4 * 4];
    #pragma unroll
    for (int u = 0; u < 8; ++u) {
      const int j = cg * 8 + u;
      wv[u] = *(const float4*)&Wl[j * DIM + ((k4 ^ ((j >> 3) & 7)) << 2)];
    }
    #pragma unroll
    for (int v = 0; v < 4; ++v)
      #pragma unroll
      for (int u = 0; u < 8; ++u) {
        acc[v][u] = fmaf(xv[v].x, wv[u].x, acc[v][u]);
        acc[v][u] = fmaf(xv[v].y, wv[u].y, acc[v][u]);
        acc[v][u] = fmaf(xv[v].z, wv[u].z, acc[v][u]);
        acc[v][u] = fmaf(xv[v].w, wv[u].w, acc[v][u]);
      }
  }

  #pragma unroll
  for (int v = 0; v < 4; ++v) {
    float pn = 0.f;
    #pragma unroll
    for (int u = 0; u < 8; ++u) {
      const float th = tanhf(acc[v][u]);   // EXACT: do not approximate
      acc[v][u] = th;
      pn = fmaf(th, th, pn);
    }
    nrm[(rg + 32 * v) * 17 + cg] = pn;
  }
  __syncthreads();
  if (t < 128) {
    float s = 0.f;
    #pragma unroll
    for (int c2 = 0; c2 < 16; ++c2) s += nrm[t * 17 + c2];
    norm2l[t] = s;
    const int row = rbase + t;
    if (row < R) {
      const float nm = sqrtf(s);
      const float sc = (nm > 0.9f) ? (0.9f / nm) : 1.0f;
      const float p2v = s * sc * sc;
      P2[row] = p2v;
      if (ismem) Pm2s[row] = fmaf(0.5f, p2v, 1.0f);
    } else if (ismem && row < npadm) {
      Pm2s[row] = __int_as_float(0x7f800000);   // +inf: exclude padded rows
    }
  }
  __syncthreads();

  #pragma unroll
  for (int v = 0; v < 4; ++v) {
    const int r = rg + 32 * v;
    const int row = rbase + r;
    if (row < R) {
      const float n2 = norm2l[r];
      const float nm = sqrtf(n2);
      const float sc = (nm > 0.9f) ? (0.9f / nm) : 1.0f;
      float o[8];
      #pragma unroll
      for (int u = 0; u < 8; ++u) o[u] = acc[v][u] * sc;
      *(float4*)&P[(size_t)row * DIM + cg * 8]     = make_float4(o[0], o[1], o[2], o[3]);
      *(float4*)&P[(size_t)row * DIM + cg * 8 + 4] = make_float4(o[4], o[5], o[6], o[7]);
      if (Pbf) {
        uint4 pb;
        pb.x = (unsigned)f2bf(o[0]) | ((unsigned)f2bf(o[1]) << 16);
        pb.y = (unsigned)f2bf(o[2]) | ((unsigned)f2bf(o[3]) << 16);
        pb.z = (unsigned)f2bf(o[4]) | ((unsigned)f2bf(o[5]) << 16);
        pb.w = (unsigned)f2bf(o[6]) | ((unsigned)f2bf(o[7]) << 16);
        // pre-swizzled store: chunk position = cg ^ (row & 15)
        *(uint4*)&Pmbf[(size_t)row * DIM + ((cg ^ (row & 15)) << 3)] = pb;
      }
    }
  }
}

// ---------------------------------------------------------------------------
// Kernel 2: bf16-MFMA approx scoring, QB=128, 3-buffer counted-vmcnt pipeline
//   (R17 structure; selection inserts now med3-based: 4 VALU vs 8).
// ---------------------------------------------------------------------------
template<bool USEBF>
__global__ __launch_bounds__(512, 2) void score_topk_k(
    const float* __restrict__ Pq,
    const float* __restrict__ Pm, const float* __restrict__ Pm2s,
    const unsigned short* __restrict__ Pmbf,
    int N, int splitlen, unsigned* __restrict__ splitTop)
{
  __shared__ __align__(16) unsigned short Ml[3][MB * DIM];  // 3 x 16 KB
  __shared__ float m2all[M2MAX];                            // 12.8 KB

  const int t = threadIdx.x;
  const int lane = t & 63;
  const int w = t >> 6, wr = w >> 1, wc = w & 1;   // 4 q-groups x 2 m-halves
  const int split = blockIdx.x;
  const int qbase = blockIdx.y * QB;
  const int mlo = split * splitlen;                // multiple of MB
  const int mhi = min(mlo + splitlen, N);
  const int ntiles = (mhi - mlo + MB - 1) / MB;

  // TWO persistent NEGATED Q fragments per wave: rows wr*32+s*16+..
  bf16x8 qf[2][4];
  #pragma unroll
  for (int s = 0; s < 2; ++s) {
    const int qrow = qbase + wr * 32 + s * 16 + (lane & 15);
    #pragma unroll
    for (int ks = 0; ks < 4; ++ks) {
      const float* src = &Pq[(size_t)qrow * DIM + ks * 32 + (lane >> 4) * 8];
      float4 lo = *(const float4*)src;
      float4 hi = *(const float4*)(src + 4);
      bf16x8 v;
      v[0] = (short)f2bf(-lo.x); v[1] = (short)f2bf(-lo.y);
      v[2] = (short)f2bf(-lo.z); v[3] = (short)f2bf(-lo.w);
      v[4] = (short)f2bf(-hi.x); v[5] = (short)f2bf(-hi.y);
      v[6] = (short)f2bf(-hi.z); v[7] = (short)f2bf(-hi.w);
      qf[s][ks] = v;
    }
  }

  // whole-split C-init values into LDS (once, before the pipeline starts)
  for (int i = t; i < splitlen; i += 512) m2all[i] = Pm2s[mlo + i];

  // staging: wave stages rows w*8 .. w*8+7 (2 x gload_lds16 of 4 rows each)
  const size_t soff0 = (size_t)(w * 8 + (lane >> 4)) * DIM + ((lane & 15) << 3);
  const size_t soff1 = soff0 + 4 * DIM;

  auto stageU = [&](int tilei, int buf) {
    const unsigned short* b = Pmbf + (size_t)(mlo + tilei * MB) * DIM;
    gload_lds16(b + soff0, &Ml[buf][(w * 8) * DIM]);
    gload_lds16(b + soff1, &Ml[buf][(w * 8 + 4) * DIM]);
  };
  // !USEBF fallback staging (fp32 -> bf16 through regs)
  uint4 sv0, sv1;
  auto stageF_load = [&](int tilei) {
    const int fr = t >> 3, fe = t & 7;
    const float* src = Pm + (size_t)(mlo + tilei * MB + fr) * DIM + fe * 16;
    float4 a0 = *(const float4*)(src + 0);
    float4 a1 = *(const float4*)(src + 4);
    float4 a2 = *(const float4*)(src + 8);
    float4 a3 = *(const float4*)(src + 12);
    sv0.x = (unsigned)f2bf(a0.x) | ((unsigned)f2bf(a0.y) << 16);
    sv0.y = (unsigned)f2bf(a0.z) | ((unsigned)f2bf(a0.w) << 16);
    sv0.z = (unsigned)f2bf(a1.x) | ((unsigned)f2bf(a1.y) << 16);
    sv0.w = (unsigned)f2bf(a1.z) | ((unsigned)f2bf(a1.w) << 16);
    sv1.x = (unsigned)f2bf(a2.x) | ((unsigned)f2bf(a2.y) << 16);
    sv1.y = (unsigned)f2bf(a2.z) | ((unsigned)f2bf(a2.w) << 16);
    sv1.z = (unsigned)f2bf(a3.x) | ((unsigned)f2bf(a3.y) << 16);
    sv1.w = (unsigned)f2bf(a3.z) | ((unsigned)f2bf(a3.w) << 16);
  };
  auto stageF_write = [&](int buf) {
    const int fr = t >> 3, fe = t & 7;
    char* base = (char*)&Ml[buf][0] + fr * 256;
    *(uint4*)(base + (((2 * fe)     ^ (fr & 15)) << 4)) = sv0;
    *(uint4*)(base + (((2 * fe + 1) ^ (fr & 15)) << 4)) = sv1;
  };

  unsigned keys[2][4][KOWN];
  #pragma unroll
  for (int s = 0; s < 2; ++s)
    #pragma unroll
    for (int r = 0; r < 4; ++r)
      #pragma unroll
      for (int i = 0; i < KOWN; ++i) keys[s][r][i] = 0xFFFFFFFFu;

  const int mcol = wc * 32 + (lane & 15);
  const int rowA = mcol, rowB = mcol + 16;

  auto compute = [&](int tile, const unsigned short* cur) {
    const float ca = m2all[tile * MB + mcol];
    const float cb = m2all[tile * MB + mcol + 16];
    // C-init: acc = 0.5*m2+1; with A = -q, result = (m2+2)/2 - dot = d2/2
    f32x4 a00 = (f32x4){ca, ca, ca, ca};
    f32x4 a01 = (f32x4){cb, cb, cb, cb};
    f32x4 a10 = (f32x4){ca, ca, ca, ca};
    f32x4 a11 = (f32x4){cb, cb, cb, cb};
    __builtin_amdgcn_s_setprio(1);
    #pragma unroll
    for (int ks = 0; ks < 4; ++ks) {
      const int kb = ks * 64 + (lane >> 4) * 16;
      bf16x8 bfrA = *(const bf16x8*)((const char*)cur + rowA * 256 +
                                     (kb ^ ((rowA & 15) << 4)));
      bf16x8 bfrB = *(const bf16x8*)((const char*)cur + rowB * 256 +
                                     (kb ^ ((rowB & 15) << 4)));
      a00 = mfma16(qf[0][ks], bfrA, a00);
      a01 = mfma16(qf[0][ks], bfrB, a01);
      a10 = mfma16(qf[1][ks], bfrA, a10);
      a11 = mfma16(qf[1][ks], bfrB, a11);
    }
    __builtin_amdgcn_s_setprio(0);
    const unsigned idx0 = (unsigned)(tile * MB + mcol);
    #pragma unroll
    for (int r = 0; r < 4; ++r) {
      ins4(keys[0][r], (__float_as_uint(a00[r]) & KEYMASK) | idx0);
      ins4(keys[0][r], (__float_as_uint(a01[r]) & KEYMASK) | (idx0 + 16));
      ins4(keys[1][r], (__float_as_uint(a10[r]) & KEYMASK) | idx0);
      ins4(keys[1][r], (__float_as_uint(a11[r]) & KEYMASK) | (idx0 + 16));
    }
  };

  if constexpr (USEBF) {
    __syncthreads();                 // m2all visible; VMEM fully drained
    stageU(0, 0);
    if (ntiles > 1) stageU(1, 1);
    int cur = 0;
    for (int i = 0; i < ntiles; ++i) {
      // my stage(i) done (stage(i+1)'s 2 ops may remain in flight)
      if (i < ntiles - 1) asm volatile("s_waitcnt vmcnt(2)" ::: "memory");
      else                asm volatile("s_waitcnt vmcnt(0)" ::: "memory");
      __builtin_amdgcn_s_barrier();  // ALL waves' stage(i) done; all
                                     // compute(i-1) reads finished
      __builtin_amdgcn_sched_barrier(0);
      int nb = cur + 2; if (nb >= 3) nb -= 3;      // buffer of tile i-1, free
      if (i + 2 < ntiles) stageU(i + 2, nb);
      compute(i, &Ml[cur][0]);
      cur = (cur + 1 == 3) ? 0 : cur + 1;
    }
  } else {
    stageF_load(0);
    stageF_write(0);
    __syncthreads();
    for (int i = 0; i < ntiles; ++i) {
      const int cur = i & 1;
      const bool more = (i + 1 < ntiles);
      if (more) stageF_load(i + 1);
      compute(i, &Ml[cur][0]);
      __syncthreads();
      if (more) stageF_write(cur ^ 1);
      __syncthreads();
    }
  }

  // ---- emission: per (s,r) q-slot 16-lane tournament -> sorted-8; the two
  // wc-groups of each q meet in LDS; wc=0 waves produce top-8 of the 16.
  unsigned* mb = (unsigned*)&Ml[0][0];            // 128 q x 16 u32 = 8 KB
  __syncthreads();                                // all tile reads done
  #pragma unroll
  for (int s = 0; s < 2; ++s)
    #pragma unroll
    for (int r = 0; r < 4; ++r) {
      unsigned k0 = keys[s][r][0], k1 = keys[s][r][1];
      unsigned k2 = keys[s][r][2], k3 = keys[s][r][3];
      unsigned out = 0xFFFFFFFFu;
      for (int round = 0; round < 8; ++round) {
        unsigned g = k0;
        g = uminu(g, __shfl_xor(g, 1, 16));
        g = uminu(g, __shfl_xor(g, 2, 16));
        g = uminu(g, __shfl_xor(g, 4, 16));
        g = uminu(g, __shfl_xor(g, 8, 16));
        const bool mine = (k0 == g);
        k0 = mine ? k1 : k0;
        k1 = mine ? k2 : k1;
        k2 = mine ? k3 : k2;
        k3 = mine ? 0xFFFFFFFFu : k3;
        if ((lane & 15) == round) out = g;
      }
      const int lq = wr * 32 + s * 16 + (lane >> 4) * 4 + r;
      if ((lane & 15) < 8) mb[lq * 16 + wc * 8 + (lane & 15)] = out;
    }
  __syncthreads();
  if (wc == 0 && lane < 32) {
    const int lq = wr * 32 + lane;
    unsigned s8[8];
    #pragma unroll
    for (int i = 0; i < 8; ++i) s8[i] = 0xFFFFFFFFu;
    const unsigned* src = mb + lq * 16;
    #pragma unroll
    for (int i = 0; i < 16; ++i) {
      const unsigned c = src[i];
      const unsigned n0 = uminu(c, s8[0]);
      const unsigned n1 = umed3(c, s8[0], s8[1]);
      const unsigned n2 = umed3(c, s8[1], s8[2]);
      const unsigned n3 = umed3(c, s8[2], s8[3]);
      const unsigned n4 = umed3(c, s8[3], s8[4]);
      const unsigned n5 = umed3(c, s8[4], s8[5]);
      const unsigned n6 = umed3(c, s8[5], s8[6]);
      const unsigned n7 = umed3(c, s8[6], s8[7]);
      s8[0] = n0; s8[1] = n1; s8[2] = n2; s8[3] = n3;
      s8[4] = n4; s8[5] = n5; s8[6] = n6; s8[7] = n7;
    }
    unsigned* dst = &splitTop[((size_t)(qbase + lq) * NSPLIT + split) * 8];
    *(uint4*)dst       = make_uint4(s8[0], s8[1], s8[2], s8[3]);
    *((uint4*)dst + 1) = make_uint4(s8[4], s8[5], s8[6], s8[7]);
  }
}

// ---------------------------------------------------------------------------
// Kernel 3: 4 queries per block, one wave per query.
//   merge 256 candidates (32 sorted-8 streams) -> approx top-32 ->
//   EXACT fp32 rescore -> top-16, softmax, gather.
// ---------------------------------------------------------------------------
__global__ __launch_bounds__(256) void finalize_k(
    const unsigned* __restrict__ splitTop,
    const float* __restrict__ Pq, const float* __restrict__ Pq2,
    const float* __restrict__ Pm, const float* __restrict__ Pm2,
    const float* __restrict__ memOut, int N, int splitlen,
    float* __restrict__ outW, float* __restrict__ outO)
{
  const int wv   = threadIdx.x >> 6;     // wave 0..3 -> query
  const int lane = threadIdx.x & 63;
  const int q = blockIdx.x * 4 + wv;

  __shared__ unsigned      sKey[4][RESCORE];
  __shared__ unsigned char sSrc[4][RESCORE];
  __shared__ unsigned long long sKeyx[4][RESCORE];
  __shared__ unsigned long long sSel[4][KSEL];
  __shared__ float sEl[4][KSEL];

  // phase A: lane < 32 owns split stream `lane` (8 keys, sorted ascending)
  {
    unsigned a[8];
    if (lane < NSPLIT) {
      const unsigned* gp = splitTop + (size_t)q * (NSPLIT * 8) + lane * 8;
      uint4 lo = *(const uint4*)gp;
      uint4 hi = *(const uint4*)(gp + 4);
      a[0] = lo.x; a[1] = lo.y; a[2] = lo.z; a[3] = lo.w;
      a[4] = hi.x; a[5] = hi.y; a[6] = hi.z; a[7] = hi.w;
    } else {
      #pragma unroll
      for (int i = 0; i < 8; ++i) a[i] = 0xFFFFFFFFu;
    }
    for (int r = 0; r < RESCORE; ++r) {
      unsigned g = a[0];
      g = uminu(g, __shfl_xor(g, 1));
      g = uminu(g, __shfl_xor(g, 2));
      g = uminu(g, __shfl_xor(g, 4));
      g = uminu(g, __shfl_xor(g, 8));
      g = uminu(g, __shfl_xor(g, 16));
      g = uminu(g, __shfl_xor(g, 32));
      unsigned long long mask = __ballot(a[0] == g);
      const int fl = __ffsll((unsigned long long)mask) - 1;
      if (lane == fl) {
        #pragma unroll
        for (int i = 0; i < 7; ++i) a[i] = a[i + 1];
        a[7] = 0xFFFFFFFFu;
      }
      if (lane == 0) { sKey[wv][r] = g; sSrc[wv][r] = (unsigned char)fl; }
    }
  }

  // phase B: exact fp32 rescore; 4 passes x 8 cands x 8 lanes each
  #pragma unroll
  for (int p = 0; p < 4; ++p) {
    const int g8 = p * 8 + (lane >> 3), e = lane & 7;
    const int gidx = (int)sSrc[wv][g8] * splitlen + (int)(sKey[wv][g8] & IDXMASK);
    const float4* qr = (const float4*)&Pq[(size_t)q * DIM];
    const float4* mr = (const float4*)&Pm[(size_t)gidx * DIM];
    float s = 0.f;
    #pragma unroll
    for (int u = 0; u < 4; ++u) {
      float4 a = qr[e * 4 + u], b = mr[e * 4 + u];
      s = fmaf(a.x, b.x, s); s = fmaf(a.y, b.y, s);
      s = fmaf(a.z, b.z, s); s = fmaf(a.w, b.w, s);
    }
    s += __shfl_xor(s, 1, 8);
    s += __shfl_xor(s, 2, 8);
    s += __shfl_xor(s, 4, 8);
    if (e == 0) {
      float d2 = (Pq2[q] + Pm2[gidx]) - 2.0f * s;
      float dist = sqrtf(fmaxf(d2, 1e-12f));
      sKeyx[wv][g8] =
          (((unsigned long long)__float_as_uint(dist)) << 32) | (unsigned)gidx;
    }
  }

  // phase C: exact top-16 of the 32 (keys unique: low bits = gidx)
  {
    unsigned long long kk = (lane < RESCORE) ? sKeyx[wv][lane] : ~0ull;
    for (int r = 0; r < KSEL; ++r) {
      unsigned long long g = kk;
      g = umin64(g, __shfl_xor(g, 1));
      g = umin64(g, __shfl_xor(g, 2));
      g = umin64(g, __shfl_xor(g, 4));
      g = umin64(g, __shfl_xor(g, 8));
      g = umin64(g, __shfl_xor(g, 16));
      g = umin64(g, __shfl_xor(g, 32));
      if (kk == g) kk = ~0ull;
      if (lane == 0) sSel[wv][r] = g;
    }
  }

  if (lane < KSEL) {
    const float d  = __uint_as_float((unsigned)(sSel[wv][lane] >> 32));
    const float d0 = __uint_as_float((unsigned)(sSel[wv][0] >> 32));
    sEl[wv][lane] = expf((d0 - d) * 10.0f);      // -(d/0.1) + d0/0.1
  }
  if (lane < KSEL) {
    float sum = 0.f;
    #pragma unroll
    for (int i = 0; i < KSEL; ++i) sum += sEl[wv][i];
    outW[(size_t)q * KSEL + lane] = sEl[wv][lane] / sum;
  }

  #pragma unroll
  for (int i = 0; i < 8; ++i) {
    const int f4 = lane + i * 64;
    const int r = f4 >> 5, c4 = f4 & 31;
    const int idx = (int)(sSel[wv][r] & 0xffffffffu);
    *(float4*)&outO[((size_t)q * KSEL + r) * DIM + c4 * 4] =
        *(const float4*)&memOut[(size_t)idx * DIM + c4 * 4];
  }
}

// ---------------------------------------------------------------------------
extern "C" void kernel_launch(void* const* d_in, const int* in_sizes, int n_in,
                              void* d_out, int out_size, void* d_ws, size_t ws_size,
                              hipStream_t stream)
{
  const float* query   = (const float*)d_in[0];
  const float* W       = (const float*)d_in[1];
  const float* bias    = (const float*)d_in[2];
  const float* mem_emb = (const float*)d_in[3];
  const float* mem_out = (const float*)d_in[4];
  const int B = in_sizes[0] / DIM;   // 2048
  const int N = in_sizes[3] / DIM;   // 100000

  // tile-aligned split length: mlo = split*splitlen is a multiple of MB
  const int splitlen = ((N + NSPLIT * MB - 1) / (NSPLIT * MB)) * MB;   // 3136
  const int N_pad2 = NSPLIT * splitlen;                                // 100352

  // ws (80.9 MB): Pm[N] | Pm2[N] | Pm2s[N_pad2] | Pq | Pq2 |
  //               splitTop[B*NSPLIT*8] | Pmbf[N_pad2*128]
  float* ws  = (float*)d_ws;
  float* Pm  = ws;
  float* Pm2 = Pm + (size_t)N * DIM;
  float* Pm2s = Pm2 + N;
  float* Pq  = Pm2s + N_pad2;
  float* Pq2 = Pq + (size_t)B * DIM;
  unsigned* splitTop = (unsigned*)(Pq2 + B);
  unsigned short* Pmbf = (unsigned short*)(splitTop + (size_t)B * NSPLIT * 8);
  const size_t need_bf = (size_t)((char*)(Pmbf + (size_t)N_pad2 * DIM) - (char*)d_ws);
  const bool usebf = ws_size >= need_bf;

  float* outW = (float*)d_out;
  float* outO = outW + (size_t)B * KSEL;

  // 1) fused Poincare transforms; grid covers padded mem rows for Pm2s +inf
  const int nbm = (N_pad2 + 127) / 128;
  const int nbq = (B + 127) / 128;
  poincare2_k<<<dim3(nbm + nbq), dim3(512), 0, stream>>>(
      mem_emb, N, query, B, W, bias, Pm, Pm2, Pm2s, N_pad2,
      usebf ? Pmbf : nullptr, Pq, Pq2, nbm);

  // 2) bf16-MFMA approx scoring + per-(q,split) top-8
  //    x = split (fast): 32%8==0 -> 4 fixed splits per XCD (3.2MB < L2)
  dim3 grid2(NSPLIT, B / QB);
  if (usebf)
    score_topk_k<true><<<grid2, dim3(512), 0, stream>>>(Pq, Pm, Pm2s, Pmbf, N,
                                                        splitlen, splitTop);
  else
    score_topk_k<false><<<grid2, dim3(512), 0, stream>>>(Pq, Pm, Pm2s, nullptr, N,
                                                         splitlen, splitTop);

  // 3) merge + exact rescore + softmax + gather (wave per query)
  finalize_k<<<dim3(B / 4), dim3(256), 0, stream>>>(splitTop, Pq, Pq2, Pm, Pm2,
                                                    mem_out, N, splitlen,
                                                    outW, outO);
}